// Round 5
// baseline (118.012 us; speedup 1.0000x reference)
//
#include <hip/hip_runtime.h>
#include <stddef.h>

// ---------------------------------------------------------------------------
// CustomNet forward. Round 5 (bisection of round-4 replay nondeterminism):
//  - conv2: round-4 restructure (kyx-outer, 4 MFMAs per A ds_read, XOR-swizzled
//    h1p) MINUS s_setprio, with tail slot position clamped in-range.
//  - fc1/fc2: reverted to exact round-3 kernels (BM=128, SPLIT=16, replay-
//    stable), using the round-4 pooled/wpack permuted layout.
// ---------------------------------------------------------------------------

#define NIMG 2048

typedef __attribute__((ext_vector_type(8))) short short8;
typedef __attribute__((ext_vector_type(4))) float f32x4;

__device__ inline ushort f2bf(float f) {
    unsigned u = __builtin_bit_cast(unsigned, f);
    unsigned r = (u + 0x7fff + ((u >> 16) & 1)) >> 16;   // RTNE, finite
    return (ushort)r;
}

// pack w2 [64][32][3][3] into per-lane MFMA B-fragments:
// bfr[((nt*9 + kyx)*64 + lane)*8 + j] = bf16(w2[oc=nt*16+(lane&15)][ic=8*(lane>>4)+j][kyx])
__global__ void k_w2pack(const float* __restrict__ w2, ushort* __restrict__ bfr) {
    int i = blockIdx.x * 256 + threadIdx.x;
    if (i < 18432) {
        int j = i & 7;
        int l = (i >> 3) & 63;
        int t = i >> 9;
        int kyx = t % 9, nt = t / 9;
        int oc = nt * 16 + (l & 15);
        int ic = 8 * (l >> 4) + j;
        bfr[i] = f2bf(w2[oc * 288 + ic * 9 + kyx]);
    }
}

// Permute fc1_w columns into the conv kernel's pooled output order (bf16).
// kp = (mt*64 + lane)*4 + nt  ->  oc=nt*16+(lane&15); qid=mt*4+(lane>>4);
// orig_k = oc*144 + qid.
__global__ void k_fc1wpack(const float* __restrict__ fc1_w, ushort* __restrict__ wp) {
    int idx = blockIdx.x * 256 + threadIdx.x;
    if (idx < 128 * 9216) {
        int n = idx / 9216, kp = idx % 9216;
        int nt = kp & 3;
        int lane = (kp >> 2) & 63;
        int mt = kp >> 8;
        int oc = nt * 16 + (lane & 15);
        int qid = mt * 4 + (lane >> 4);
        wp[idx] = f2bf(fc1_w[(size_t)n * 9216 + oc * 144 + qid]);
    }
}

// swizzled h1p byte address for (position q, 16B-group g)
#define SWZB(q, g) ((((q) << 6) | ((g) << 4)) ^ (((q) & 14) << 3))

__launch_bounds__(512)
__global__ void k_conv_fused(const float* __restrict__ x,
                             const float* __restrict__ w1,
                             const float* __restrict__ b1,
                             const ushort* __restrict__ bfr,
                             const float* __restrict__ b2,
                             ushort* __restrict__ pooled) {   // bf16, permuted k
    __shared__ char smem[46400];          // h1p 43264 B + xs 3136 B
    float* xs = (float*)(smem + 43264);
    const int tid = threadIdx.x;
    const int img = blockIdx.x;
    const int lane = tid & 63;
    const int w = tid >> 6;

    // ---- stage x ----
    const float* xg = x + (size_t)img * 784;
    for (int i = tid; i < 784; i += 512) xs[i] = xg[i];

    // ---- conv1 weights/bias in registers ----
    const int ocg = tid & 3;
    float w1r[72], b1r[8];
    #pragma unroll
    for (int j = 0; j < 8; j++) {
        b1r[j] = b1[ocg * 8 + j];
        #pragma unroll
        for (int q = 0; q < 9; q++) w1r[j * 9 + q] = w1[(ocg * 8 + j) * 9 + q];
    }
    __syncthreads();

    // ---- conv1 + relu -> swizzled h1p[pos][ic] bf16 ----
    #pragma unroll
    for (int it = 0; it < 3; it++) {
        int pid = (tid >> 2) + it * 128;
        if (pid < 338) {
            int y = pid / 13;
            int px2 = (pid - y * 13) * 2;
            const float* xr = &xs[y * 28 + px2];
            float xv[3][4];
            #pragma unroll
            for (int r = 0; r < 3; r++) {
                float2 u = *(const float2*)&xr[r * 28];
                float2 v = *(const float2*)&xr[r * 28 + 2];
                xv[r][0] = u.x; xv[r][1] = u.y; xv[r][2] = v.x; xv[r][3] = v.y;
            }
            short8 pk0, pk1;
            #pragma unroll
            for (int j = 0; j < 8; j++) {
                float s0 = b1r[j], s1 = b1r[j];
                #pragma unroll
                for (int ky = 0; ky < 3; ky++)
                    #pragma unroll
                    for (int kx = 0; kx < 3; kx++) {
                        float wv = w1r[j * 9 + ky * 3 + kx];
                        s0 = fmaf(wv, xv[ky][kx], s0);
                        s1 = fmaf(wv, xv[ky][kx + 1], s1);
                    }
                pk0[j] = (short)f2bf(fmaxf(s0, 0.0f));
                pk1[j] = (short)f2bf(fmaxf(s1, 0.0f));
            }
            int pos0 = y * 26 + px2;
            *(short8*)(smem + SWZB(pos0, ocg)) = pk0;
            *(short8*)(smem + SWZB(pos0 + 1, ocg)) = pk1;
        }
    }
    __syncthreads();

    // ---- conv2 MFMA: wave w owns m-slots {w+8i} (+ 32+w for w<4), all 4 nt ----
    const int row = lane & 15;
    const int ic8 = lane >> 4;
    const bool tail = (w < 4);

    int posb[5], mts[5];
    #pragma unroll
    for (int i = 0; i < 5; i++) {
        // clamp the unused tail slot to a valid mt so no OOB address ever forms
        int mt = (i < 4) ? (w + 8 * i) : (tail ? (32 + w) : w);
        mts[i] = mt;
        int m = mt * 16 + row;
        int qid = m >> 2, de = m & 3;
        int py = qid / 12, px = qid - py * 12;
        posb[i] = (2 * py + (de >> 1)) * 26 + 2 * px + (de & 1);
    }

    float b2v[4];
    #pragma unroll
    for (int nt = 0; nt < 4; nt++) b2v[nt] = b2[nt * 16 + row];

    f32x4 acc[5][4];
    #pragma unroll
    for (int i = 0; i < 5; i++)
        #pragma unroll
        for (int nt = 0; nt < 4; nt++) acc[i][nt] = (f32x4){0.f, 0.f, 0.f, 0.f};

    #pragma unroll
    for (int ky = 0; ky < 3; ky++)
        #pragma unroll
        for (int kx = 0; kx < 3; kx++) {
            const int kyx = ky * 3 + kx;
            short8 bfv[4];
            #pragma unroll
            for (int nt = 0; nt < 4; nt++)
                bfv[nt] = *(const short8*)&bfr[(((nt * 9 + kyx) * 64) + lane) * 8];
            #pragma unroll
            for (int i = 0; i < 5; i++) {
                if (i < 4 || tail) {
                    int q = posb[i] + ky * 26 + kx;
                    short8 a = *(const short8*)(smem + SWZB(q, ic8));
                    #pragma unroll
                    for (int nt = 0; nt < 4; nt++)
                        acc[i][nt] = __builtin_amdgcn_mfma_f32_16x16x32_bf16(a, bfv[nt], acc[i][nt], 0, 0, 0);
                }
            }
        }

    // ---- maxpool + bias + relu + packed bf16 store (8B/lane, coalesced) ----
    uint2* pp = (uint2*)(pooled + (size_t)img * 9216);
    #pragma unroll
    for (int i = 0; i < 5; i++) {
        if (i < 4 || tail) {
            float v[4];
            #pragma unroll
            for (int nt = 0; nt < 4; nt++) {
                f32x4 a = acc[i][nt];
                v[nt] = fmaxf(fmaxf(fmaxf(a[0], a[1]), fmaxf(a[2], a[3])) + b2v[nt], 0.0f);
            }
            uint2 o;
            o.x = (unsigned)f2bf(v[0]) | ((unsigned)f2bf(v[1]) << 16);
            o.y = (unsigned)f2bf(v[2]) | ((unsigned)f2bf(v[3]) << 16);
            pp[mts[i] * 64 + lane] = o;
        }
    }
}

// fc1: bf16 MFMA split-K GEMM (exact round-3 kernel, replay-stable).
// M=2048, N=128, K=9216 (permuted). grid (16 m-tiles, 16 k-splits),
// block 512 (8 waves, 2x4), BM=128 BN=128 BK=64.
#define FC1_SPLIT 16
#define FC1_CHUNK 576   // 9 BK-steps of 64

__launch_bounds__(512)
__global__ void k_fc1(const ushort* __restrict__ A,    // pooled bf16 [2048][9216]
                      const ushort* __restrict__ Wp,   // packed fc1_w bf16 [128][9216]
                      float* __restrict__ part) {      // [16][2048][128]
    __shared__ ushort As[128 * 64];
    __shared__ ushort Ws[128 * 64];
    char* Ac = (char*)As;
    char* Wc = (char*)Ws;

    const int t = threadIdx.x;
    const int lane = t & 63;
    const int wv = t >> 6;
    const int wm = wv >> 2;        // 0..1
    const int wn = wv & 3;         // 0..3
    const int lr = lane & 15;
    const int lk = lane >> 4;
    const int m0 = blockIdx.x * 128;
    const int kc0 = blockIdx.y * FC1_CHUNK;

    const int trow = t >> 2;       // 0..127
    const int seg = t & 3;         // 0..3
    const int wb0 = trow * 128 + seg * 32;
    const int sw = (trow & 7) << 4;

    const ushort* Ab = A + (size_t)(m0 + trow) * 9216 + kc0 + seg * 16;
    const ushort* Wb = Wp + (size_t)trow * 9216 + kc0 + seg * 16;

    f32x4 acc[4][2];
    #pragma unroll
    for (int mf = 0; mf < 4; mf++)
        #pragma unroll
        for (int nf = 0; nf < 2; nf++) acc[mf][nf] = (f32x4){0.f, 0.f, 0.f, 0.f};

    short8 ra0 = *(const short8*)(Ab);
    short8 ra1 = *(const short8*)(Ab + 8);
    short8 rw0 = *(const short8*)(Wb);
    short8 rw1 = *(const short8*)(Wb + 8);
    short8 na0, na1, nw0, nw1;

    for (int s = 0; s < 9; s++) {
        *(short8*)(Ac + (wb0 ^ sw)) = ra0;
        *(short8*)(Ac + ((wb0 + 16) ^ sw)) = ra1;
        *(short8*)(Wc + (wb0 ^ sw)) = rw0;
        *(short8*)(Wc + ((wb0 + 16) ^ sw)) = rw1;
        __syncthreads();
        if (s < 8) {
            const ushort* An = Ab + (s + 1) * 64;
            const ushort* Wn = Wb + (s + 1) * 64;
            na0 = *(const short8*)(An);
            na1 = *(const short8*)(An + 8);
            nw0 = *(const short8*)(Wn);
            nw1 = *(const short8*)(Wn + 8);
        }
        #pragma unroll
        for (int ks = 0; ks < 2; ks++) {
            short8 af[4], bfr2[2];
            #pragma unroll
            for (int mf = 0; mf < 4; mf++) {
                int r = wm * 64 + mf * 16 + lr;
                af[mf] = *(const short8*)(Ac + ((r * 128 + ks * 64 + lk * 16) ^ ((r & 7) << 4)));
            }
            #pragma unroll
            for (int nf = 0; nf < 2; nf++) {
                int n = wn * 32 + nf * 16 + lr;
                bfr2[nf] = *(const short8*)(Wc + ((n * 128 + ks * 64 + lk * 16) ^ ((n & 7) << 4)));
            }
            #pragma unroll
            for (int mf = 0; mf < 4; mf++)
                #pragma unroll
                for (int nf = 0; nf < 2; nf++)
                    acc[mf][nf] = __builtin_amdgcn_mfma_f32_16x16x32_bf16(af[mf], bfr2[nf], acc[mf][nf], 0, 0, 0);
        }
        __syncthreads();
        if (s < 8) { ra0 = na0; ra1 = na1; rw0 = nw0; rw1 = nw1; }
    }

    float* pb = part + (size_t)blockIdx.y * (2048 * 128);
    #pragma unroll
    for (int mf = 0; mf < 4; mf++)
        #pragma unroll
        for (int nf = 0; nf < 2; nf++) {
            int mrow = m0 + wm * 64 + mf * 16 + lk * 4;
            int ncol = wn * 32 + nf * 16 + lr;
            #pragma unroll
            for (int q = 0; q < 4; q++)
                pb[(size_t)(mrow + q) * 128 + ncol] = acc[mf][nf][q];
        }
}

// fc2: reduce split-K partials + fc1 bias + relu, then 128->10 GEMV.
__global__ void k_fc2(const float* __restrict__ part,   // [16][2048][128]
                      const float* __restrict__ fc1_b,
                      const float* __restrict__ fc2_w,  // [10][128]
                      const float* __restrict__ fc2_b,
                      float* __restrict__ out) {        // [2048][10]
    __shared__ float hs[16 * 128];
    __shared__ float wsm[10 * 128];
    __shared__ float bsm[10];
    const int t = threadIdx.x;
    const int m0 = blockIdx.x * 16;
    for (int i = t; i < 1280; i += 256) wsm[i] = fc2_w[i];
    if (t < 10) bsm[t] = fc2_b[t];
    #pragma unroll
    for (int e = 0; e < 8; e++) {
        int i = t + e * 256;
        int r = i >> 7, c = i & 127;
        float s = fc1_b[c];
        #pragma unroll
        for (int kc = 0; kc < FC1_SPLIT; kc++)
            s += part[(size_t)kc * (2048 * 128) + (size_t)(m0 + r) * 128 + c];
        hs[i] = fmaxf(s, 0.0f);
    }
    __syncthreads();
    int r = t / 16, c = t % 16;
    if (c < 10) {
        float s = bsm[c];
        const float* hp = &hs[r * 128];
        const float* wp = &wsm[c * 128];
        #pragma unroll
        for (int k = 0; k < 128; k++) s = fmaf(hp[k], wp[k], s);
        out[(size_t)(m0 + r) * 10 + c] = s;
    }
}

extern "C" void kernel_launch(void* const* d_in, const int* in_sizes, int n_in,
                              void* d_out, int out_size, void* d_ws, size_t ws_size,
                              hipStream_t stream) {
    const float* x     = (const float*)d_in[0];
    const float* w1    = (const float*)d_in[1];
    const float* b1    = (const float*)d_in[2];
    const float* w2    = (const float*)d_in[3];
    const float* b2    = (const float*)d_in[4];
    const float* fc1_w = (const float*)d_in[5];
    const float* fc1_b = (const float*)d_in[6];
    const float* fc2_w = (const float*)d_in[7];
    const float* fc2_b = (const float*)d_in[8];
    float* out = (float*)d_out;

    char* wsb = (char*)d_ws;
    ushort* bfr    = (ushort*)wsb;                       // 36864 B
    ushort* wp     = (ushort*)(wsb + 36864);             // 2359296 B
    ushort* pooled = (ushort*)(wsb + 2396160);           // 37748736 B
    float*  part   = (float*)(wsb + 40144896);           // 16777216 B

    k_w2pack<<<72, 256, 0, stream>>>(w2, bfr);
    k_fc1wpack<<<4608, 256, 0, stream>>>(fc1_w, wp);
    k_conv_fused<<<NIMG, 512, 0, stream>>>(x, w1, b1, bfr, b2, pooled);
    k_fc1<<<dim3(16, FC1_SPLIT), 512, 0, stream>>>(pooled, wp, part);
    k_fc2<<<NIMG / 16, 256, 0, stream>>>(part, fc1_b, fc2_w, fc2_b, out);
}

// Round 6
// 115.201 us; speedup vs baseline: 1.0244x; 1.0244x over previous
//
#include <hip/hip_runtime.h>
#include <stddef.h>

// ---------------------------------------------------------------------------
// CustomNet forward. Round 6:
//  - conv2: mfma_f32_32x32x16_bf16 (2x FLOP per A ds_read), B-fragments staged
//    in LDS (no global loads in MFMA loop), 8 waves x 2 m-tiles x 2 n-tiles,
//    phase-2 for tiles 16/17. XOR-swizzled h1p. In-lane 2x2 pool (regs 4q..4q+3).
//  - fc1/fc2: byte-identical to round-3/5 (replay-proven); only the k-order
//    permutation in k_fc1wpack changes to match the new conv output layout.
// ---------------------------------------------------------------------------

#define NIMG 2048

typedef __attribute__((ext_vector_type(8))) short short8;
typedef __attribute__((ext_vector_type(4))) float f32x4;
typedef __attribute__((ext_vector_type(16))) float f32x16;

__device__ inline ushort f2bf(float f) {
    unsigned u = __builtin_bit_cast(unsigned, f);
    unsigned r = (u + 0x7fff + ((u >> 16) & 1)) >> 16;   // RTNE, finite
    return (ushort)r;
}

// pack w2 [64][32][3][3] into 32x32x16 MFMA B-fragments:
// bfr32[((nt*18 + kyx*2 + ich)*64 + l)*8 + j]
//   = bf16(w2[oc = nt*32 + (l&31)][ic = ich*16 + 8*(l>>5) + j][kyx])
__global__ void k_w2pack32(const float* __restrict__ w2, ushort* __restrict__ bfr) {
    int i = blockIdx.x * 256 + threadIdx.x;
    if (i < 18432) {
        int j = i & 7;
        int l = (i >> 3) & 63;
        int t = i >> 9;            // nt*18 + kyx*2 + ich
        int nt = t / 18, r = t % 18;
        int kyx = r >> 1, ich = r & 1;
        int oc = nt * 32 + (l & 31);
        int ic = ich * 16 + 8 * (l >> 5) + j;
        bfr[i] = f2bf(w2[oc * 288 + ic * 9 + kyx]);
    }
}

// Permute fc1_w columns into the conv kernel's pooled output order (bf16).
// kp = qid*64 + col*2 + nt  ->  oc = nt*32 + col; orig_k = oc*144 + qid.
__global__ void k_fc1wpack(const float* __restrict__ fc1_w, ushort* __restrict__ wp) {
    int idx = blockIdx.x * 256 + threadIdx.x;
    if (idx < 128 * 9216) {
        int n = idx / 9216, kp = idx % 9216;
        int nt = kp & 1;
        int col = (kp >> 1) & 31;
        int qid = kp >> 6;
        int oc = nt * 32 + col;
        wp[idx] = f2bf(fc1_w[(size_t)n * 9216 + oc * 144 + qid]);
    }
}

// swizzled h1p byte address for (position q, 16B-group g)
#define SWZB(q, g) ((((q) << 6) | ((g) << 4)) ^ (((q) & 14) << 3))

// LDS: [0,43264) h1p swizzled; [43264,80128) B-fragments; [80128,83264) xs
#define BOFF 43264
#define XOFF 80128

__launch_bounds__(512)
__global__ void k_conv_fused(const float* __restrict__ x,
                             const float* __restrict__ w1,
                             const float* __restrict__ b1,
                             const ushort* __restrict__ bfr,
                             const float* __restrict__ b2,
                             ushort* __restrict__ pooled) {   // bf16, permuted k
    __shared__ char smem[83264];
    float* xs = (float*)(smem + XOFF);
    const int tid = threadIdx.x;
    const int img = blockIdx.x;
    const int lane = tid & 63;
    const int w = tid >> 6;

    // ---- stage x + B-fragments (B region untouched by conv1) ----
    const float* xg = x + (size_t)img * 784;
    for (int i = tid; i < 784; i += 512) xs[i] = xg[i];
    {
        uint4* bd = (uint4*)(smem + BOFF);
        const uint4* bsrc = (const uint4*)bfr;
        for (int i = tid; i < 2304; i += 512) bd[i] = bsrc[i];
    }

    // ---- conv1 weights/bias in registers ----
    const int ocg = tid & 3;
    float w1r[72], b1r[8];
    #pragma unroll
    for (int j = 0; j < 8; j++) {
        b1r[j] = b1[ocg * 8 + j];
        #pragma unroll
        for (int q = 0; q < 9; q++) w1r[j * 9 + q] = w1[(ocg * 8 + j) * 9 + q];
    }
    __syncthreads();

    // ---- conv1 + relu -> swizzled h1p[pos][ic] bf16 ----
    #pragma unroll
    for (int it = 0; it < 3; it++) {
        int pid = (tid >> 2) + it * 128;
        if (pid < 338) {
            int y = pid / 13;
            int px2 = (pid - y * 13) * 2;
            const float* xr = &xs[y * 28 + px2];
            float xv[3][4];
            #pragma unroll
            for (int r = 0; r < 3; r++) {
                float2 u = *(const float2*)&xr[r * 28];
                float2 v = *(const float2*)&xr[r * 28 + 2];
                xv[r][0] = u.x; xv[r][1] = u.y; xv[r][2] = v.x; xv[r][3] = v.y;
            }
            short8 pk0, pk1;
            #pragma unroll
            for (int j = 0; j < 8; j++) {
                float s0 = b1r[j], s1 = b1r[j];
                #pragma unroll
                for (int ky = 0; ky < 3; ky++)
                    #pragma unroll
                    for (int kx = 0; kx < 3; kx++) {
                        float wv = w1r[j * 9 + ky * 3 + kx];
                        s0 = fmaf(wv, xv[ky][kx], s0);
                        s1 = fmaf(wv, xv[ky][kx + 1], s1);
                    }
                pk0[j] = (short)f2bf(fmaxf(s0, 0.0f));
                pk1[j] = (short)f2bf(fmaxf(s1, 0.0f));
            }
            int pos0 = y * 26 + px2;
            *(short8*)(smem + SWZB(pos0, ocg)) = pk0;
            *(short8*)(smem + SWZB(pos0 + 1, ocg)) = pk1;
        }
    }
    __syncthreads();

    // ---- conv2 via 32x32x16 MFMA ----
    // A: row = lane&31 -> conv position m; k = 8*(lane>>5)+j -> ic within 16.
    // C/D: col(N=oc) = lane&31, row(M) = (reg&3) + 8*(reg>>2) + 4*(lane>>5).
    const int col = lane & 31;
    const int hi  = lane >> 5;

    float b2v[2];
    b2v[0] = b2[col];
    b2v[1] = b2[32 + col];

    uint* pg = (uint*)(pooled + (size_t)img * 9216);

    // phase 1: wave w owns m-tiles {2w, 2w+1}, both n-tiles
    int posS[2];
    #pragma unroll
    for (int ms = 0; ms < 2; ms++) {
        int m = (2 * w + ms) * 32 + col;
        int qid = m >> 2, de = m & 3;
        int py = qid / 12, px = qid - py * 12;
        posS[ms] = (2 * py + (de >> 1)) * 26 + 2 * px + (de & 1);
    }

    f32x16 acc[2][2];
    #pragma unroll
    for (int ms = 0; ms < 2; ms++)
        #pragma unroll
        for (int nt = 0; nt < 2; nt++)
            #pragma unroll
            for (int e = 0; e < 16; e++) acc[ms][nt][e] = 0.0f;

    #pragma unroll
    for (int ky = 0; ky < 3; ky++)
        #pragma unroll
        for (int kx = 0; kx < 3; kx++)
            #pragma unroll
            for (int ich = 0; ich < 2; ich++) {
                const int ks = (ky * 3 + kx) * 2 + ich;
                short8 bf0 = *(const short8*)(smem + BOFF + ks * 1024 + lane * 16);
                short8 bf1 = *(const short8*)(smem + BOFF + (18 + ks) * 1024 + lane * 16);
                #pragma unroll
                for (int ms = 0; ms < 2; ms++) {
                    short8 a = *(const short8*)(smem + SWZB(posS[ms] + ky * 26 + kx, ich * 2 + hi));
                    acc[ms][0] = __builtin_amdgcn_mfma_f32_32x32x16_bf16(a, bf0, acc[ms][0], 0, 0, 0);
                    acc[ms][1] = __builtin_amdgcn_mfma_f32_32x32x16_bf16(a, bf1, acc[ms][1], 0, 0, 0);
                }
            }

    // pool (regs 4q..4q+3 = one 2x2 quad) + bias + relu + packed store
    #pragma unroll
    for (int ms = 0; ms < 2; ms++)
        #pragma unroll
        for (int q = 0; q < 4; q++) {
            float v0 = fmaxf(fmaxf(acc[ms][0][4 * q], acc[ms][0][4 * q + 1]),
                             fmaxf(acc[ms][0][4 * q + 2], acc[ms][0][4 * q + 3]));
            float v1 = fmaxf(fmaxf(acc[ms][1][4 * q], acc[ms][1][4 * q + 1]),
                             fmaxf(acc[ms][1][4 * q + 2], acc[ms][1][4 * q + 3]));
            v0 = fmaxf(v0 + b2v[0], 0.0f);
            v1 = fmaxf(v1 + b2v[1], 0.0f);
            int qid = (2 * w + ms) * 8 + hi + 2 * q;
            pg[qid * 32 + col] = (unsigned)f2bf(v0) | ((unsigned)f2bf(v1) << 16);
        }

    // phase 2: waves 0,1 handle m-tiles 16,17 (acc registers now free)
    if (w < 2) {
        int mt = 16 + w;
        int m = mt * 32 + col;
        int qid0 = m >> 2, de = m & 3;
        int py = qid0 / 12, px = qid0 - py * 12;
        int posT = (2 * py + (de >> 1)) * 26 + 2 * px + (de & 1);

        f32x16 a2[2];
        #pragma unroll
        for (int nt = 0; nt < 2; nt++)
            #pragma unroll
            for (int e = 0; e < 16; e++) a2[nt][e] = 0.0f;

        #pragma unroll
        for (int ky = 0; ky < 3; ky++)
            #pragma unroll
            for (int kx = 0; kx < 3; kx++)
                #pragma unroll
                for (int ich = 0; ich < 2; ich++) {
                    const int ks = (ky * 3 + kx) * 2 + ich;
                    short8 bf0 = *(const short8*)(smem + BOFF + ks * 1024 + lane * 16);
                    short8 bf1 = *(const short8*)(smem + BOFF + (18 + ks) * 1024 + lane * 16);
                    short8 a = *(const short8*)(smem + SWZB(posT + ky * 26 + kx, ich * 2 + hi));
                    a2[0] = __builtin_amdgcn_mfma_f32_32x32x16_bf16(a, bf0, a2[0], 0, 0, 0);
                    a2[1] = __builtin_amdgcn_mfma_f32_32x32x16_bf16(a, bf1, a2[1], 0, 0, 0);
                }

        #pragma unroll
        for (int q = 0; q < 4; q++) {
            float v0 = fmaxf(fmaxf(a2[0][4 * q], a2[0][4 * q + 1]),
                             fmaxf(a2[0][4 * q + 2], a2[0][4 * q + 3]));
            float v1 = fmaxf(fmaxf(a2[1][4 * q], a2[1][4 * q + 1]),
                             fmaxf(a2[1][4 * q + 2], a2[1][4 * q + 3]));
            v0 = fmaxf(v0 + b2v[0], 0.0f);
            v1 = fmaxf(v1 + b2v[1], 0.0f);
            int qid = mt * 8 + hi + 2 * q;
            pg[qid * 32 + col] = (unsigned)f2bf(v0) | ((unsigned)f2bf(v1) << 16);
        }
    }
}

// fc1: bf16 MFMA split-K GEMM (exact round-3/5 kernel, replay-stable).
#define FC1_SPLIT 16
#define FC1_CHUNK 576   // 9 BK-steps of 64

__launch_bounds__(512)
__global__ void k_fc1(const ushort* __restrict__ A,    // pooled bf16 [2048][9216]
                      const ushort* __restrict__ Wp,   // packed fc1_w bf16 [128][9216]
                      float* __restrict__ part) {      // [16][2048][128]
    __shared__ ushort As[128 * 64];
    __shared__ ushort Ws[128 * 64];
    char* Ac = (char*)As;
    char* Wc = (char*)Ws;

    const int t = threadIdx.x;
    const int lane = t & 63;
    const int wv = t >> 6;
    const int wm = wv >> 2;        // 0..1
    const int wn = wv & 3;         // 0..3
    const int lr = lane & 15;
    const int lk = lane >> 4;
    const int m0 = blockIdx.x * 128;
    const int kc0 = blockIdx.y * FC1_CHUNK;

    const int trow = t >> 2;       // 0..127
    const int seg = t & 3;         // 0..3
    const int wb0 = trow * 128 + seg * 32;
    const int sw = (trow & 7) << 4;

    const ushort* Ab = A + (size_t)(m0 + trow) * 9216 + kc0 + seg * 16;
    const ushort* Wb = Wp + (size_t)trow * 9216 + kc0 + seg * 16;

    f32x4 acc[4][2];
    #pragma unroll
    for (int mf = 0; mf < 4; mf++)
        #pragma unroll
        for (int nf = 0; nf < 2; nf++) acc[mf][nf] = (f32x4){0.f, 0.f, 0.f, 0.f};

    short8 ra0 = *(const short8*)(Ab);
    short8 ra1 = *(const short8*)(Ab + 8);
    short8 rw0 = *(const short8*)(Wb);
    short8 rw1 = *(const short8*)(Wb + 8);
    short8 na0, na1, nw0, nw1;

    for (int s = 0; s < 9; s++) {
        *(short8*)(Ac + (wb0 ^ sw)) = ra0;
        *(short8*)(Ac + ((wb0 + 16) ^ sw)) = ra1;
        *(short8*)(Wc + (wb0 ^ sw)) = rw0;
        *(short8*)(Wc + ((wb0 + 16) ^ sw)) = rw1;
        __syncthreads();
        if (s < 8) {
            const ushort* An = Ab + (s + 1) * 64;
            const ushort* Wn = Wb + (s + 1) * 64;
            na0 = *(const short8*)(An);
            na1 = *(const short8*)(An + 8);
            nw0 = *(const short8*)(Wn);
            nw1 = *(const short8*)(Wn + 8);
        }
        #pragma unroll
        for (int ks = 0; ks < 2; ks++) {
            short8 af[4], bfr2[2];
            #pragma unroll
            for (int mf = 0; mf < 4; mf++) {
                int r = wm * 64 + mf * 16 + lr;
                af[mf] = *(const short8*)(Ac + ((r * 128 + ks * 64 + lk * 16) ^ ((r & 7) << 4)));
            }
            #pragma unroll
            for (int nf = 0; nf < 2; nf++) {
                int n = wn * 32 + nf * 16 + lr;
                bfr2[nf] = *(const short8*)(Wc + ((n * 128 + ks * 64 + lk * 16) ^ ((n & 7) << 4)));
            }
            #pragma unroll
            for (int mf = 0; mf < 4; mf++)
                #pragma unroll
                for (int nf = 0; nf < 2; nf++)
                    acc[mf][nf] = __builtin_amdgcn_mfma_f32_16x16x32_bf16(af[mf], bfr2[nf], acc[mf][nf], 0, 0, 0);
        }
        __syncthreads();
        if (s < 8) { ra0 = na0; ra1 = na1; rw0 = nw0; rw1 = nw1; }
    }

    float* pb = part + (size_t)blockIdx.y * (2048 * 128);
    #pragma unroll
    for (int mf = 0; mf < 4; mf++)
        #pragma unroll
        for (int nf = 0; nf < 2; nf++) {
            int mrow = m0 + wm * 64 + mf * 16 + lk * 4;
            int ncol = wn * 32 + nf * 16 + lr;
            #pragma unroll
            for (int q = 0; q < 4; q++)
                pb[(size_t)(mrow + q) * 128 + ncol] = acc[mf][nf][q];
        }
}

// fc2: reduce split-K partials + fc1 bias + relu, then 128->10 GEMV.
__global__ void k_fc2(const float* __restrict__ part,   // [16][2048][128]
                      const float* __restrict__ fc1_b,
                      const float* __restrict__ fc2_w,  // [10][128]
                      const float* __restrict__ fc2_b,
                      float* __restrict__ out) {        // [2048][10]
    __shared__ float hs[16 * 128];
    __shared__ float wsm[10 * 128];
    __shared__ float bsm[10];
    const int t = threadIdx.x;
    const int m0 = blockIdx.x * 16;
    for (int i = t; i < 1280; i += 256) wsm[i] = fc2_w[i];
    if (t < 10) bsm[t] = fc2_b[t];
    #pragma unroll
    for (int e = 0; e < 8; e++) {
        int i = t + e * 256;
        int r = i >> 7, c = i & 127;
        float s = fc1_b[c];
        #pragma unroll
        for (int kc = 0; kc < FC1_SPLIT; kc++)
            s += part[(size_t)kc * (2048 * 128) + (size_t)(m0 + r) * 128 + c];
        hs[i] = fmaxf(s, 0.0f);
    }
    __syncthreads();
    int r = t / 16, c = t % 16;
    if (c < 10) {
        float s = bsm[c];
        const float* hp = &hs[r * 128];
        const float* wp = &wsm[c * 128];
        #pragma unroll
        for (int k = 0; k < 128; k++) s = fmaf(hp[k], wp[k], s);
        out[(size_t)(m0 + r) * 10 + c] = s;
    }
}

extern "C" void kernel_launch(void* const* d_in, const int* in_sizes, int n_in,
                              void* d_out, int out_size, void* d_ws, size_t ws_size,
                              hipStream_t stream) {
    const float* x     = (const float*)d_in[0];
    const float* w1    = (const float*)d_in[1];
    const float* b1    = (const float*)d_in[2];
    const float* w2    = (const float*)d_in[3];
    const float* b2    = (const float*)d_in[4];
    const float* fc1_w = (const float*)d_in[5];
    const float* fc1_b = (const float*)d_in[6];
    const float* fc2_w = (const float*)d_in[7];
    const float* fc2_b = (const float*)d_in[8];
    float* out = (float*)d_out;

    char* wsb = (char*)d_ws;
    ushort* bfr    = (ushort*)wsb;                       // 36864 B
    ushort* wp     = (ushort*)(wsb + 36864);             // 2359296 B
    ushort* pooled = (ushort*)(wsb + 2396160);           // 37748736 B
    float*  part   = (float*)(wsb + 40144896);           // 16777216 B

    k_w2pack32<<<72, 256, 0, stream>>>(w2, bfr);
    k_fc1wpack<<<4608, 256, 0, stream>>>(fc1_w, wp);
    k_conv_fused<<<NIMG, 512, 0, stream>>>(x, w1, b1, bfr, b2, pooled);
    k_fc1<<<dim3(16, FC1_SPLIT), 512, 0, stream>>>(pooled, wp, part);
    k_fc2<<<NIMG / 16, 256, 0, stream>>>(part, fc1_b, fc2_w, fc2_b, out);
}